// Round 5
// baseline (380.773 us; speedup 1.0000x reference)
//
#include <hip/hip_runtime.h>

typedef float v2f __attribute__((ext_vector_type(2)));

#define HS   1024
#define SEQ  512
#define NBAT 64
#define INSZ 8
#define NM   4
#define DD   12

// DPP-based add: v += dpp_move(v). old=0, bound_ctrl=true.
#define DPP_ADD(v, ctrl, rmask, bmask) \
  v += __int_as_float(__builtin_amdgcn_update_dpp(0, __float_as_int(v), ctrl, rmask, bmask, true))

// Canonical gfx9 wave64 sum; lane 63 holds the 64-lane total afterwards.
__device__ __forceinline__ void wave64_sum2(float &a, float &b){
  DPP_ADD(a, 0x111, 0xf, 0xf); DPP_ADD(b, 0x111, 0xf, 0xf);  // row_shr:1
  DPP_ADD(a, 0x112, 0xf, 0xf); DPP_ADD(b, 0x112, 0xf, 0xf);  // row_shr:2
  DPP_ADD(a, 0x114, 0xf, 0xe); DPP_ADD(b, 0x114, 0xf, 0xe);  // row_shr:4
  DPP_ADD(a, 0x118, 0xf, 0xc); DPP_ADD(b, 0x118, 0xf, 0xc);  // row_shr:8
  DPP_ADD(a, 0x142, 0xa, 0xf); DPP_ADD(b, 0x142, 0xa, 0xf);  // row_bcast:15
  DPP_ADD(a, 0x143, 0xc, 0xf); DPP_ADD(b, 0x143, 0xc, 0xf);  // row_bcast:31
}

__device__ __forceinline__ float bcast63(float v){
  return __int_as_float(__builtin_amdgcn_readlane(__float_as_int(v), 63));
}

__device__ __forceinline__ v2f fma2(v2f a, v2f b, v2f c){
  return __builtin_elementwise_fma(a, b, c);   // v_pk_fma_f32
}

// One wave per batch. State is 10 lane-uniform scalars (a in R^2, b in R^8):
//   h_t = m*a_t + I*b_t  (exact: h0=0 is in col(span), updates stay in it)
//   a' = 0.9a + alpha*s*U,  b' = 0.9b + alpha*x_t,  out[t] = (a', b')
// Per step the 1024 rows appear only in U = N - 2*sum_i rcp(e^{2h_i}+1)*n_i,
// reduced fully in-wave (DPP butterfly) -> NO LDS/barrier/poll in the loop.
__global__ __launch_bounds__(64,1)
void rnn_scan(const float* __restrict__ x,
              const float* __restrict__ eps,
              const float* __restrict__ means,
              const float* __restrict__ tril,
              const float* __restrict__ mw,
              float* __restrict__ out)
{
  const int b    = blockIdx.x;
  const int lane = threadIdx.x;   // 0..63

  __shared__ __align__(16) float xs[SEQ*INSZ + 8];   // +pad for t=511 prefetch

  // stage x[b] (one-time, coalesced float4)
  {
    const float4* src = (const float4*)(x + b*SEQ*INSZ);
    float4* dst = (float4*)xs;
    for (int i = lane; i < SEQ*INSZ/4; i += 64) dst[i] = src[i];
  }

  // ---- mixture weights ----
  float w[NM];
  {
    float s = 0.f;
    #pragma unroll
    for (int k=0;k<NM;k++){ w[k] = fmaxf(mw[k], 1e-6f); s += w[k]; }
    float inv = 1.0f/s;
    #pragma unroll
    for (int k=0;k<NM;k++) w[k] *= inv;
  }

  // SC = 2*log2(e): h~ = SC*(m*a + I*b) so v_exp_f32(h~) = 2^h~ = e^{2h}
  const float SC = 2.8853900817779268f;

  // ---- preprocessing: lane owns contiguous rows 16*lane..16*lane+15, packed
  // in pairs. m,I pre-scaled by SC; n unscaled. ----
  v2f mp0[8], mp1[8], np0[8], np1[8], Ip[8][8];
  float nn0 = 0.f, nn1 = 0.f;
  #pragma unroll
  for (int p=0;p<8;p++){
    float rowmix[2][DD];
    #pragma unroll
    for (int h2=0; h2<2; h2++){
      const int i = lane*16 + 2*p + h2;
      float ep[NM][DD];
      #pragma unroll
      for (int k=0;k<NM;k++){
        const float4* p4 = (const float4*)(eps + (size_t)(k*HS + i)*DD);
        float4 q0=p4[0], q1=p4[1], q2=p4[2];
        ep[k][0]=q0.x; ep[k][1]=q0.y; ep[k][2]=q0.z; ep[k][3]=q0.w;
        ep[k][4]=q1.x; ep[k][5]=q1.y; ep[k][6]=q1.z; ep[k][7]=q1.w;
        ep[k][8]=q2.x; ep[k][9]=q2.y; ep[k][10]=q2.z; ep[k][11]=q2.w;
      }
      #pragma unroll
      for (int e=0;e<DD;e++){
        float a = 0.f;
        #pragma unroll
        for (int k=0;k<NM;k++){
          float se = means[k*DD+e];
          for (int d=0; d<e; d++)                       // strict lower tri
            se += ep[k][d]*tril[(k*DD+e)*DD + d];
          float dg = fabsf(tril[(k*DD+e)*DD + e] - 1e-12f) + 1e-12f;
          se += ep[k][e]*dg;
          a += w[k]*se;
        }
        rowmix[h2][e] = a;
      }
    }
    mp0[p] = (v2f){SC*rowmix[0][0], SC*rowmix[1][0]};
    mp1[p] = (v2f){SC*rowmix[0][1], SC*rowmix[1][1]};
    np0[p] = (v2f){rowmix[0][2], rowmix[1][2]};
    np1[p] = (v2f){rowmix[0][3], rowmix[1][3]};
    nn0 += rowmix[0][2] + rowmix[1][2];
    nn1 += rowmix[0][3] + rowmix[1][3];
    #pragma unroll
    for (int e=0;e<8;e++)
      Ip[p][e] = (v2f){SC*rowmix[0][4+e], SC*rowmix[1][4+e]};
  }
  wave64_sum2(nn0, nn1);
  const float N0 = bcast63(nn0);
  const float N1 = bcast63(nn1);

  __syncthreads();   // xs visible (single wave: compiles to a waitcnt)

  const float alpha = 0.1f;
  const float oma   = 0.9f;
  const float as    = 0.1f*500.0f/1024.0f;   // alpha * BASE_SCALE/HIDDEN

  float a0 = 0.f, a1 = 0.f;
  v2f bb[8];
  #pragma unroll
  for (int e=0;e<8;e++) bb[e] = (v2f){0.f,0.f};

  float4 xA = *(const float4*)&xs[0];
  float4 xB = *(const float4*)&xs[4];

  float* outp = out + (size_t)b*SEQ*10;

  for (int t=0;t<SEQ;t++){
    const v2f A0 = (v2f){a0,a0};
    const v2f A1 = (v2f){a1,a1};
    v2f S0 = (v2f){0.f,0.f}, S1 = (v2f){0.f,0.f};
    #pragma unroll
    for (int p=0;p<8;p++){
      v2f v = Ip[p][0]*bb[0];
      v = fma2(Ip[p][1], bb[1], v);
      v = fma2(Ip[p][2], bb[2], v);
      v = fma2(Ip[p][3], bb[3], v);
      v = fma2(Ip[p][4], bb[4], v);
      v = fma2(Ip[p][5], bb[5], v);
      v = fma2(Ip[p][6], bb[6], v);
      v = fma2(Ip[p][7], bb[7], v);
      v = fma2(mp0[p], A0, v);
      v = fma2(mp1[p], A1, v);          // v = SC*(m_i.a + I_i.b) = h~
      float e0 = __builtin_amdgcn_exp2f(v.x);   // v_exp_f32: 2^h~ = e^{2h}
      float e1 = __builtin_amdgcn_exp2f(v.y);
      v2f r = (v2f){ __builtin_amdgcn_rcpf(e0+1.0f),
                     __builtin_amdgcn_rcpf(e1+1.0f) };   // r=1/(e^{2h}+1)
      S0 = fma2(r, np0[p], S0);
      S1 = fma2(r, np1[p], S1);
    }
    float s0 = S0.x + S0.y;
    float s1 = S1.x + S1.y;
    wave64_sum2(s0, s1);
    s0 = bcast63(s0);
    s1 = bcast63(s1);
    const float U0 = __builtin_fmaf(-2.0f, s0, N0);  // tanh = 1-2r
    const float U1 = __builtin_fmaf(-2.0f, s1, N1);

    a0 = __builtin_fmaf(oma, a0, as*U0);
    a1 = __builtin_fmaf(oma, a1, as*U1);

    float xv[8] = {xA.x,xA.y,xA.z,xA.w, xB.x,xB.y,xB.z,xB.w};
    #pragma unroll
    for (int e=0;e<8;e++){
      float ax = alpha*xv[e];
      bb[e] = fma2(bb[e], (v2f){oma,oma}, (v2f){ax,ax});
    }

    // prefetch next x (off-chain; pad covers t=511)
    xA = *(const float4*)&xs[(t+1)*8];
    xB = *(const float4*)&xs[(t+1)*8+4];

    // out[b,t,:] = (a', b') -- fire-and-forget 8B stores, never waited in-loop
    if (lane==0){
      float2* op = (float2*)(outp + t*10);
      op[0] = make_float2(a0, a1);
      op[1] = make_float2(bb[0].x, bb[1].x);
      op[2] = make_float2(bb[2].x, bb[3].x);
      op[3] = make_float2(bb[4].x, bb[5].x);
      op[4] = make_float2(bb[6].x, bb[7].x);
    }
  }
}

extern "C" void kernel_launch(void* const* d_in, const int* in_sizes, int n_in,
                              void* d_out, int out_size, void* d_ws, size_t ws_size,
                              hipStream_t stream) {
  const float* x     = (const float*)d_in[0];  // (64,512,8)
  const float* eps   = (const float*)d_in[1];  // (4,1024,12)
  const float* means = (const float*)d_in[2];  // (4,12)
  const float* tril  = (const float*)d_in[3];  // (4,12,12)
  const float* mw    = (const float*)d_in[4];  // (4,)
  float* out = (float*)d_out;                  // (64,512,10) fp32

  rnn_scan<<<NBAT, 64, 0, stream>>>(x, eps, means, tril, mw, out);
}